// Round 1
// baseline (155.255 us; speedup 1.0000x reference)
//
#include <hip/hip_runtime.h>
#include <hip/hip_bf16.h>
#include <stdint.h>

#define CH   384
#define HID  512
#define NHD  8
#define MTOT 32768   // B*H*W tokens

typedef __attribute__((ext_vector_type(8))) short bf16x8;
typedef __attribute__((ext_vector_type(4))) float f32x4;
typedef unsigned short u16;

__device__ __forceinline__ float bf2f(u16 v){ return __uint_as_float(((unsigned)v)<<16); }
__device__ __forceinline__ u16 f2bf(float f){
  unsigned u = __float_as_uint(f);
  return (u16)((u + 0x7fffu + ((u>>16)&1u)) >> 16);
}
__device__ __forceinline__ void gload_lds16(const void* g, void* l){
  __builtin_amdgcn_global_load_lds((const __attribute__((address_space(1))) void*)g,
                                   (__attribute__((address_space(3))) void*)l, 16, 0, 0);
}

// ---------------- fp32 -> bf16 convert ----------------
__global__ void k_cvt(const float* __restrict__ in, u16* __restrict__ out, int n4){
  int i = blockIdx.x*blockDim.x + threadIdx.x;
  int stride = gridDim.x*blockDim.x;
  for (; i < n4; i += stride){
    float4 v = ((const float4*)in)[i];
    ushort4 o; o.x=f2bf(v.x); o.y=f2bf(v.y); o.z=f2bf(v.z); o.w=f2bf(v.w);
    ((ushort4*)out)[i] = o;
  }
}

// ---------------- GEMM1: proj = x@W1^T + b1, fused split + x*tanh(s) ----------------
// grid (MTOT/128, 512/32), 256 thr. Per block: 128 rows x (32 h-cols x 3 segments).
__global__ void k_gemm1(const u16* __restrict__ xb, const u16* __restrict__ w1b,
                        const float* __restrict__ b1,
                        u16* __restrict__ xh, u16* __restrict__ yb)
{
  __shared__ short lA[128*64];   // 16 KB
  __shared__ short lB[96*64];    // 12 KB
  const int tid = threadIdx.x;
  const int w = tid >> 6, lw = tid & 63;
  const int m0 = blockIdx.x * 128;
  const int h0 = blockIdx.y * 32;

  f32x4 acc[2][6] = {};

  for (int kt = 0; kt < CH/64; ++kt){
    const int kbase = kt*64;
    // A tile: 16 chunks of 1024B, swizzled source (LDS[row][s] = G[row][s^(row&7)])
    #pragma unroll
    for (int i = 0; i < 4; ++i){
      int chunk = i*4 + w;
      int row = chunk*8 + (lw>>3);
      int sl  = (lw&7) ^ (row&7);
      gload_lds16(xb + (size_t)(m0+row)*CH + kbase + sl*8, &lA[chunk*512]);
    }
    // B tile: 12 chunks; rows 0-31 seg0(h), 32-63 seg1(512+h), 64-95 seg2(1024+h)
    #pragma unroll
    for (int i = 0; i < 3; ++i){
      int chunk = i*4 + w;
      int row = chunk*8 + (lw>>3);
      int grow = (row>>5)*HID + h0 + (row&31);
      int sl = (lw&7) ^ (row&7);
      gload_lds16(w1b + (size_t)grow*CH + kbase + sl*8, &lB[chunk*512]);
    }
    __syncthreads();
    #pragma unroll
    for (int ks = 0; ks < 2; ++ks){
      bf16x8 af[2], bfr[6];
      #pragma unroll
      for (int mi=0; mi<2; ++mi){
        int row = w*32 + mi*16 + (lw&15);
        int sl = (ks*4 + (lw>>4)) ^ (row&7);
        af[mi] = *(const bf16x8*)&lA[row*64 + sl*8];
      }
      #pragma unroll
      for (int nj=0; nj<6; ++nj){
        int row = nj*16 + (lw&15);
        int sl = (ks*4 + (lw>>4)) ^ (row&7);
        bfr[nj] = *(const bf16x8*)&lB[row*64 + sl*8];
      }
      #pragma unroll
      for (int mi=0; mi<2; ++mi)
        #pragma unroll
        for (int nj=0; nj<6; ++nj)
          acc[mi][nj] = __builtin_amdgcn_mfma_f32_16x16x32_bf16(af[mi], bfr[nj], acc[mi][nj], 0,0,0);
    }
    __syncthreads();
  }

  const int lc = lw & 15, lr4 = (lw>>4)*4;
  #pragma unroll
  for (int f=0; f<2; ++f){
    int col = h0 + f*16 + lc;
    float bs = b1[col], bx = b1[512+col], by = b1[1024+col];
    #pragma unroll
    for (int mi=0; mi<2; ++mi){
      #pragma unroll
      for (int j=0; j<4; ++j){
        int row = m0 + w*32 + mi*16 + lr4 + j;
        float s  = acc[mi][0+f][j] + bs;
        float xv = (acc[mi][2+f][j] + bx) * tanhf(s);
        float yv = acc[mi][4+f][j] + by;
        xh[(size_t)row*HID + col] = f2bf(xv);
        yb[(size_t)row*HID + col] = f2bf(yv);
      }
    }
  }
}

// ---------------- Attention: one wave per (head, batch, block) ----------------
// out[q][d] = sum_t attn[q][t] * kv[t][d]; fused z = out*y written bf16.
__global__ void k_attn(const float* __restrict__ aw, const float* __restrict__ wts,
                       const int* __restrict__ idxs,
                       const u16* __restrict__ xh, const u16* __restrict__ yb,
                       u16* __restrict__ zb)
{
  __shared__ short lAt[64*120];  // attn bf16, row pad 120 (15KB)
  __shared__ short lKv[64*96];   // kv^T [d][t] with XOR swizzle (12KB)
  const int tid = threadIdx.x;            // 0..63, one wave
  const int bid = blockIdx.x;             // ((h*8+b)*64+n)
  const int h = bid >> 9;
  const int b = (bid >> 6) & 7;
  const int n = bid & 63;
  const int bh = n >> 3, bw = n & 7;

  // stage attn (64x96 fp32 -> bf16)
  {
    const float4* src = (const float4*)(aw + (size_t)bid * (64*96));
    #pragma unroll
    for (int i=0; i<24; ++i){
      int f4 = i*64 + tid;           // 0..1535
      int q = f4/24, c = f4 - q*24;
      float4 v = src[f4];
      ushort4 o; o.x=f2bf(v.x); o.y=f2bf(v.y); o.z=f2bf(v.z); o.w=f2bf(v.w);
      *(ushort4*)&lAt[q*120 + c*4] = o;
    }
  }
  // stage kv^T: tokens 0-63 block-local, 64-95 gathered*weight
  {
    const int dg = tid & 7;
    #pragma unroll
    for (int it=0; it<12; ++it){
      int t = it*8 + (tid>>3);
      size_t srow; float scale;
      if (t < 64){
        int pix = (bh*8 + (t>>3))*64 + bw*8 + (t&7);
        srow = (size_t)b*4096 + pix; scale = 1.f;
      } else {
        int e = (b*64+n)*32 + (t-64);
        srow = (size_t)b*4096 + idxs[e];
        scale = wts[e];
      }
      bf16x8 v = *(const bf16x8*)&xh[srow*HID + h*64 + dg*8];
      #pragma unroll
      for (int j2=0; j2<8; ++j2){
        int d = dg*8 + j2;
        float f = bf2f((u16)v[j2]) * scale;
        lKv[(d*96 + t) ^ (dg<<3)] = (short)f2bf(f);
      }
    }
  }
  __syncthreads();

  f32x4 acc[4][4] = {};
  const int lc = tid & 15, lk = tid >> 4;
  #pragma unroll
  for (int ks=0; ks<3; ++ks){
    bf16x8 af[4], bv[4];
    #pragma unroll
    for (int mi=0; mi<4; ++mi)
      af[mi] = *(const bf16x8*)&lAt[(mi*16+lc)*120 + ks*32 + lk*8];
    #pragma unroll
    for (int nj=0; nj<4; ++nj){
      int d = nj*16 + lc;
      int idx = (d*96 + ks*32 + lk*8) ^ ((d>>3)<<3);
      bv[nj] = *(const bf16x8*)&lKv[idx];
    }
    #pragma unroll
    for (int mi=0; mi<4; ++mi)
      #pragma unroll
      for (int nj=0; nj<4; ++nj)
        acc[mi][nj] = __builtin_amdgcn_mfma_f32_16x16x32_bf16(af[mi], bv[nj], acc[mi][nj], 0,0,0);
  }

  // epilogue: z = out * y (bf16)
  #pragma unroll
  for (int mi=0; mi<4; ++mi){
    #pragma unroll
    for (int nj=0; nj<4; ++nj){
      int d = nj*16 + lc;
      size_t gcol = (size_t)h*64 + d;
      #pragma unroll
      for (int j=0; j<4; ++j){
        int q = mi*16 + lk*4 + j;
        int pix = (bh*8 + (q>>3))*64 + bw*8 + (q&7);
        size_t r = (size_t)b*4096 + pix;
        float yv = bf2f(yb[r*HID + gcol]);
        zb[r*HID + gcol] = f2bf(acc[mi][nj][j] * yv);
      }
    }
  }
}

// ---------------- GEMM2: out = z@W2^T + b2 (fp32 out) ----------------
// grid (MTOT/128, 384/128), 256 thr, waves 2x2 of 64x64.
__global__ void k_gemm2(const u16* __restrict__ zb, const u16* __restrict__ w2b,
                        const float* __restrict__ b2, float* __restrict__ out)
{
  __shared__ short lA[128*64];
  __shared__ short lB[128*64];
  const int tid = threadIdx.x;
  const int w = tid>>6, lw = tid&63;
  const int wm = w>>1, wn = w&1;
  const int m0 = blockIdx.x*128, n0 = blockIdx.y*128;

  f32x4 acc[4][4] = {};

  for (int kt=0; kt<HID/64; ++kt){
    int kbase = kt*64;
    #pragma unroll
    for (int i=0; i<4; ++i){
      int chunk = i*4 + w;
      int row = chunk*8 + (lw>>3);
      int sl = (lw&7) ^ (row&7);
      gload_lds16(zb  + (size_t)(m0+row)*HID + kbase + sl*8, &lA[chunk*512]);
      gload_lds16(w2b + (size_t)(n0+row)*HID + kbase + sl*8, &lB[chunk*512]);
    }
    __syncthreads();
    #pragma unroll
    for (int ks=0; ks<2; ++ks){
      bf16x8 af[4], bb[4];
      #pragma unroll
      for (int mi=0; mi<4; ++mi){
        int row = wm*64 + mi*16 + (lw&15);
        int sl = (ks*4 + (lw>>4)) ^ (row&7);
        af[mi] = *(const bf16x8*)&lA[row*64 + sl*8];
      }
      #pragma unroll
      for (int nj=0; nj<4; ++nj){
        int row = wn*64 + nj*16 + (lw&15);
        int sl = (ks*4 + (lw>>4)) ^ (row&7);
        bb[nj] = *(const bf16x8*)&lB[row*64 + sl*8];
      }
      #pragma unroll
      for (int mi=0; mi<4; ++mi)
        #pragma unroll
        for (int nj=0; nj<4; ++nj)
          acc[mi][nj] = __builtin_amdgcn_mfma_f32_16x16x32_bf16(af[mi], bb[nj], acc[mi][nj], 0,0,0);
    }
    __syncthreads();
  }

  const int lc = lw&15, lr4 = (lw>>4)*4;
  #pragma unroll
  for (int nj=0; nj<4; ++nj){
    int col = n0 + wn*64 + nj*16 + lc;
    float bias = b2[col];
    #pragma unroll
    for (int mi=0; mi<4; ++mi){
      #pragma unroll
      for (int j=0; j<4; ++j){
        int row = m0 + wm*64 + mi*16 + lr4 + j;
        out[(size_t)row*CH + col] = acc[mi][nj][j] + bias;
      }
    }
  }
}

extern "C" void kernel_launch(void* const* d_in, const int* in_sizes, int n_in,
                              void* d_out, int out_size, void* d_ws, size_t ws_size,
                              hipStream_t stream) {
  const float* x   = (const float*)d_in[0];
  const float* aw  = (const float*)d_in[1];
  const float* wts = (const float*)d_in[2];
  const float* w1  = (const float*)d_in[3];
  const float* b1  = (const float*)d_in[4];
  const float* w2  = (const float*)d_in[5];
  const float* b2  = (const float*)d_in[6];
  const int*   idx = (const int*)d_in[7];
  float* out = (float*)d_out;

  char* ws = (char*)d_ws;
  u16* x_bf  = (u16*)(ws);                              // 32768*384*2  = 25165824
  u16* w1_bf = (u16*)(ws + 25165824);                   // 1536*384*2   = 1179648
  u16* w2_bf = (u16*)(ws + 26345472);                   // 384*512*2    = 393216
  u16* xh_bf = (u16*)(ws + 26738688);                   // 32768*512*2  = 33554432
  u16* y_bf  = (u16*)(ws + 60293120);                   // 33554432
  u16* z_bf  = (u16*)(ws + 93847552);                   // 33554432  (total 127402 KB)

  k_cvt<<<2048, 256, 0, stream>>>(x,  x_bf,  MTOT*CH/4);
  k_cvt<<<576,  256, 0, stream>>>(w1, w1_bf, 3*HID*CH/4);
  k_cvt<<<192,  256, 0, stream>>>(w2, w2_bf, CH*HID/4);

  k_gemm1<<<dim3(MTOT/128, HID/32), 256, 0, stream>>>(x_bf, w1_bf, b1, xh_bf, y_bf);
  k_attn<<<NHD*8*64, 64, 0, stream>>>(aw, wts, idx, xh_bf, y_bf, z_bf);
  k_gemm2<<<dim3(MTOT/128, CH/128), 256, 0, stream>>>(z_bf, w2_bf, b2, out);
}

// Round 2
// 151.067 us; speedup vs baseline: 1.0277x; 1.0277x over previous
//
#include <hip/hip_runtime.h>
#include <hip/hip_bf16.h>
#include <stdint.h>

#define CH   384
#define HID  512
#define NHD  8
#define MTOT 32768   // B*H*W tokens

typedef __attribute__((ext_vector_type(8))) short bf16x8;
typedef __attribute__((ext_vector_type(4))) float f32x4;
typedef unsigned short u16;

__device__ __forceinline__ float bf2f(u16 v){ return __uint_as_float(((unsigned)v)<<16); }
__device__ __forceinline__ u16 f2bf(float f){
  unsigned u = __float_as_uint(f);
  return (u16)((u + 0x7fffu + ((u>>16)&1u)) >> 16);
}
__device__ __forceinline__ void gload_lds16(const void* g, void* l){
  __builtin_amdgcn_global_load_lds((const __attribute__((address_space(1))) void*)g,
                                   (__attribute__((address_space(3))) void*)l, 16, 0, 0);
}

// ---------------- fp32 -> bf16 convert ----------------
__global__ void k_cvt(const float* __restrict__ in, u16* __restrict__ out, int n4){
  int i = blockIdx.x*blockDim.x + threadIdx.x;
  int stride = gridDim.x*blockDim.x;
  for (; i < n4; i += stride){
    float4 v = ((const float4*)in)[i];
    ushort4 o; o.x=f2bf(v.x); o.y=f2bf(v.y); o.z=f2bf(v.z); o.w=f2bf(v.w);
    ((ushort4*)out)[i] = o;
  }
}

// ---------------- GEMM1: proj = x@W1^T + b1, fused split + x*tanh(s) ----------------
__global__ void k_gemm1(const u16* __restrict__ xb, const u16* __restrict__ w1b,
                        const float* __restrict__ b1,
                        u16* __restrict__ xh, u16* __restrict__ yb)
{
  __shared__ short lA[128*64];   // 16 KB
  __shared__ short lB[96*64];    // 12 KB
  const int tid = threadIdx.x;
  const int w = tid >> 6, lw = tid & 63;
  const int m0 = blockIdx.x * 128;
  const int h0 = blockIdx.y * 32;

  f32x4 acc[2][6] = {};

  for (int kt = 0; kt < CH/64; ++kt){
    const int kbase = kt*64;
    #pragma unroll
    for (int i = 0; i < 4; ++i){
      int chunk = i*4 + w;
      int row = chunk*8 + (lw>>3);
      int sl  = (lw&7) ^ (row&7);
      gload_lds16(xb + (size_t)(m0+row)*CH + kbase + sl*8, &lA[chunk*512]);
    }
    #pragma unroll
    for (int i = 0; i < 3; ++i){
      int chunk = i*4 + w;
      int row = chunk*8 + (lw>>3);
      int grow = (row>>5)*HID + h0 + (row&31);
      int sl = (lw&7) ^ (row&7);
      gload_lds16(w1b + (size_t)grow*CH + kbase + sl*8, &lB[chunk*512]);
    }
    __syncthreads();
    #pragma unroll
    for (int ks = 0; ks < 2; ++ks){
      bf16x8 af[2], bfr[6];
      #pragma unroll
      for (int mi=0; mi<2; ++mi){
        int row = w*32 + mi*16 + (lw&15);
        int sl = (ks*4 + (lw>>4)) ^ (row&7);
        af[mi] = *(const bf16x8*)&lA[row*64 + sl*8];
      }
      #pragma unroll
      for (int nj=0; nj<6; ++nj){
        int row = nj*16 + (lw&15);
        int sl = (ks*4 + (lw>>4)) ^ (row&7);
        bfr[nj] = *(const bf16x8*)&lB[row*64 + sl*8];
      }
      #pragma unroll
      for (int mi=0; mi<2; ++mi)
        #pragma unroll
        for (int nj=0; nj<6; ++nj)
          acc[mi][nj] = __builtin_amdgcn_mfma_f32_16x16x32_bf16(af[mi], bfr[nj], acc[mi][nj], 0,0,0);
    }
    __syncthreads();
  }

  const int lc = lw & 15, lr4 = (lw>>4)*4;
  #pragma unroll
  for (int f=0; f<2; ++f){
    int col = h0 + f*16 + lc;
    float bs = b1[col], bx = b1[512+col], by = b1[1024+col];
    #pragma unroll
    for (int mi=0; mi<2; ++mi){
      #pragma unroll
      for (int j=0; j<4; ++j){
        int row = m0 + w*32 + mi*16 + lr4 + j;
        float s  = acc[mi][0+f][j] + bs;
        float xv = (acc[mi][2+f][j] + bx) * tanhf(s);
        float yv = acc[mi][4+f][j] + by;
        xh[(size_t)row*HID + col] = f2bf(xv);
        yb[(size_t)row*HID + col] = f2bf(yv);
      }
    }
  }
}

// ---------------- Attention v2: one wave per (head, batch, block) ----------------
// No attn LDS (direct A-frag loads from global, w folded into attn cols 64-95).
// kvT staged as bf16 pairs (b32 writes). z = (attn@kv)*y fused.
__global__ __launch_bounds__(64, 3)
void k_attn(const float* __restrict__ aw, const float* __restrict__ wts,
            const int* __restrict__ idxs,
            const u16* __restrict__ xh, const u16* __restrict__ yb,
            u16* __restrict__ zb)
{
  __shared__ short lKv[64*96];   // kv^T [d][t], XOR-swizzled, 12 KB
  const int tid = threadIdx.x;   // one wave
  const int bid = blockIdx.x;    // ((h*8+b)*64+n)
  const int h = bid >> 9;
  const int b = (bid >> 6) & 7;
  const int n = bid & 63;
  const int bh = n >> 3, bw = n & 7;

  // ---- stage kv^T: 48 token-pairs x 8 dim-groups, pure bf16 copy ----
  {
    const int dg = tid & 7;      // dim group (8 dims each)
    const int pr = tid >> 3;     // pair slot within iter
    #pragma unroll
    for (int it = 0; it < 6; ++it){
      int pair = it*8 + pr;      // 0..47
      int t0 = pair*2;
      size_t r0, r1;
      if (t0 < 64){
        int pix = (bh*8 + (t0>>3))*64 + bw*8 + (t0&7);
        r0 = (size_t)b*4096 + pix;
        r1 = r0 + 1;             // t0 even → same 8-group, pix+1
      } else {
        int e = (b*64+n)*32 + (t0-64);
        r0 = (size_t)b*4096 + idxs[e];
        r1 = (size_t)b*4096 + idxs[e+1];
      }
      bf16x8 v0 = *(const bf16x8*)&xh[r0*HID + h*64 + dg*8];
      bf16x8 v1 = *(const bf16x8*)&xh[r1*HID + h*64 + dg*8];
      #pragma unroll
      for (int j = 0; j < 8; ++j){
        int d = dg*8 + j;
        int elem = (d*96 + t0) ^ (dg<<3);   // XOR swizzle, pair-preserving
        unsigned pk = (unsigned)(u16)v0[j] | ((unsigned)(u16)v1[j] << 16);
        *(unsigned*)&lKv[elem] = pk;
      }
    }
  }

  // ---- A-fragments direct from global fp32, w folded into k-step 2 ----
  float wv[8];
  {
    const float* wp = wts + (size_t)(b*64+n)*32 + (tid>>4)*8;
    float4 a = *(const float4*)wp, c = *(const float4*)(wp+4);
    wv[0]=a.x; wv[1]=a.y; wv[2]=a.z; wv[3]=a.w;
    wv[4]=c.x; wv[5]=c.y; wv[6]=c.z; wv[7]=c.w;
  }
  const float* awp = aw + (size_t)bid * (64*96);
  bf16x8 af[3][4];
  #pragma unroll
  for (int ks = 0; ks < 3; ++ks){
    #pragma unroll
    for (int mi = 0; mi < 4; ++mi){
      const float* p = awp + (size_t)(mi*16 + (tid&15))*96 + ks*32 + (tid>>4)*8;
      float4 f0 = *(const float4*)p;
      float4 f1 = *(const float4*)(p+4);
      float t[8] = {f0.x,f0.y,f0.z,f0.w,f1.x,f1.y,f1.z,f1.w};
      #pragma unroll
      for (int j = 0; j < 8; ++j){
        float v = (ks == 2) ? t[j]*wv[j] : t[j];
        af[ks][mi][j] = (short)f2bf(v);
      }
    }
  }
  __syncthreads();

  // ---- MFMA: 64x96 @ 96x64 ----
  f32x4 acc[4][4] = {};
  const int lc = tid & 15, lk = tid >> 4;
  #pragma unroll
  for (int ks = 0; ks < 3; ++ks){
    bf16x8 bv[4];
    #pragma unroll
    for (int nj = 0; nj < 4; ++nj){
      int d = nj*16 + lc;
      int idx = (d*96 + ks*32 + lk*8) ^ ((d>>3)<<3);
      bv[nj] = *(const bf16x8*)&lKv[idx];
    }
    #pragma unroll
    for (int mi = 0; mi < 4; ++mi)
      #pragma unroll
      for (int nj = 0; nj < 4; ++nj)
        acc[mi][nj] = __builtin_amdgcn_mfma_f32_16x16x32_bf16(af[ks][mi], bv[nj], acc[mi][nj], 0,0,0);
  }

  // ---- epilogue: z = out * y (bf16) ----
  #pragma unroll
  for (int mi = 0; mi < 4; ++mi){
    #pragma unroll
    for (int nj = 0; nj < 4; ++nj){
      int d = nj*16 + lc;
      size_t gcol = (size_t)h*64 + d;
      #pragma unroll
      for (int j = 0; j < 4; ++j){
        int q = mi*16 + lk*4 + j;
        int pix = (bh*8 + (q>>3))*64 + bw*8 + (q&7);
        size_t r = (size_t)b*4096 + pix;
        float yv = bf2f(yb[r*HID + gcol]);
        zb[r*HID + gcol] = f2bf(acc[mi][nj][j] * yv);
      }
    }
  }
}

// ---------------- GEMM2: out = z@W2^T + b2 (fp32 out) ----------------
__global__ void k_gemm2(const u16* __restrict__ zb, const u16* __restrict__ w2b,
                        const float* __restrict__ b2, float* __restrict__ out)
{
  __shared__ short lA[128*64];
  __shared__ short lB[128*64];
  const int tid = threadIdx.x;
  const int w = tid>>6, lw = tid&63;
  const int wm = w>>1, wn = w&1;
  const int m0 = blockIdx.x*128, n0 = blockIdx.y*128;

  f32x4 acc[4][4] = {};

  for (int kt=0; kt<HID/64; ++kt){
    int kbase = kt*64;
    #pragma unroll
    for (int i=0; i<4; ++i){
      int chunk = i*4 + w;
      int row = chunk*8 + (lw>>3);
      int sl = (lw&7) ^ (row&7);
      gload_lds16(zb  + (size_t)(m0+row)*HID + kbase + sl*8, &lA[chunk*512]);
      gload_lds16(w2b + (size_t)(n0+row)*HID + kbase + sl*8, &lB[chunk*512]);
    }
    __syncthreads();
    #pragma unroll
    for (int ks=0; ks<2; ++ks){
      bf16x8 af[4], bb[4];
      #pragma unroll
      for (int mi=0; mi<4; ++mi){
        int row = wm*64 + mi*16 + (lw&15);
        int sl = (ks*4 + (lw>>4)) ^ (row&7);
        af[mi] = *(const bf16x8*)&lA[row*64 + sl*8];
      }
      #pragma unroll
      for (int nj=0; nj<4; ++nj){
        int row = wn*64 + nj*16 + (lw&15);
        int sl = (ks*4 + (lw>>4)) ^ (row&7);
        bb[nj] = *(const bf16x8*)&lB[row*64 + sl*8];
      }
      #pragma unroll
      for (int mi=0; mi<4; ++mi)
        #pragma unroll
        for (int nj=0; nj<4; ++nj)
          acc[mi][nj] = __builtin_amdgcn_mfma_f32_16x16x32_bf16(af[mi], bb[nj], acc[mi][nj], 0,0,0);
    }
    __syncthreads();
  }

  const int lc = lw&15, lr4 = (lw>>4)*4;
  #pragma unroll
  for (int nj=0; nj<4; ++nj){
    int col = n0 + wn*64 + nj*16 + lc;
    float bias = b2[col];
    #pragma unroll
    for (int mi=0; mi<4; ++mi){
      #pragma unroll
      for (int j=0; j<4; ++j){
        int row = m0 + wm*64 + mi*16 + lr4 + j;
        out[(size_t)row*CH + col] = acc[mi][nj][j] + bias;
      }
    }
  }
}

extern "C" void kernel_launch(void* const* d_in, const int* in_sizes, int n_in,
                              void* d_out, int out_size, void* d_ws, size_t ws_size,
                              hipStream_t stream) {
  const float* x   = (const float*)d_in[0];
  const float* aw  = (const float*)d_in[1];
  const float* wts = (const float*)d_in[2];
  const float* w1  = (const float*)d_in[3];
  const float* b1  = (const float*)d_in[4];
  const float* w2  = (const float*)d_in[5];
  const float* b2  = (const float*)d_in[6];
  const int*   idx = (const int*)d_in[7];
  float* out = (float*)d_out;

  char* ws = (char*)d_ws;
  u16* x_bf  = (u16*)(ws);                              // 32768*384*2  = 25165824
  u16* w1_bf = (u16*)(ws + 25165824);                   // 1536*384*2   = 1179648
  u16* w2_bf = (u16*)(ws + 26345472);                   // 384*512*2    = 393216
  u16* xh_bf = (u16*)(ws + 26738688);                   // 32768*512*2  = 33554432
  u16* y_bf  = (u16*)(ws + 60293120);                   // 33554432
  u16* z_bf  = (u16*)(ws + 93847552);                   // 33554432

  k_cvt<<<2048, 256, 0, stream>>>(x,  x_bf,  MTOT*CH/4);
  k_cvt<<<576,  256, 0, stream>>>(w1, w1_bf, 3*HID*CH/4);
  k_cvt<<<192,  256, 0, stream>>>(w2, w2_bf, CH*HID/4);

  k_gemm1<<<dim3(MTOT/128, HID/32), 256, 0, stream>>>(x_bf, w1_bf, b1, xh_bf, y_bf);
  k_attn<<<NHD*8*64, 64, 0, stream>>>(aw, wts, idx, xh_bf, y_bf, z_bf);
  k_gemm2<<<dim3(MTOT/128, CH/128), 256, 0, stream>>>(z_bf, w2_bf, b2, out);
}